// Round 9
// baseline (686.879 us; speedup 1.0000x reference)
//
#include <hip/hip_runtime.h>
#include <hip/hip_bf16.h>

// ---------------- problem constants ----------------
#define B_ 2
#define F_ 16
#define Hs 32
#define Ws 32
#define C0 320
#define CEXP 512
#define D_INNER 1024
#define NHEADS 16
#define HEADDIM 64
#define D_STATE 128
#define D_CONV 4
#define CONV_DIM (D_INNER + 2*D_STATE)              // 1280
#define D_IN_PROJ (2*D_INNER + 2*D_STATE + NHEADS)  // 2320
#define NPAD 2432                                   // 19*128 padded in_proj rows
#define C0PAD 384                                   // 3*128 padded 320-row weights
#define GROUPS 32
#define NB (B_*F_)        // 32 frames
#define HW (Hs*Ws)        // 1024 spatial
#define NSEQ (B_*HW)      // 2048 sequences
#define NTOK (NSEQ*F_)    // 32768 tokens
#define NCHUNK 4
#define SEQ_PER (NSEQ/NCHUNK)   // 512
#define TOK_PER (SEQ_PER*F_)    // 8192

typedef __bf16 bf16x8 __attribute__((ext_vector_type(8)));
typedef float f32x4 __attribute__((ext_vector_type(4)));
typedef __attribute__((address_space(3))) void lds_void;
typedef const __attribute__((address_space(1))) void glb_void;

// ---------------- GroupNorm (f32 frames) ----------------
__global__ __launch_bounds__(256) void gn_kernel(const float* __restrict__ x,
    const float* __restrict__ w, const float* __restrict__ b, float* __restrict__ out)
{
  const int CG = C0/GROUPS;            // 10
  const int NEL = CG*HW;               // 10240
  int g = blockIdx.x, n = blockIdx.y;
  const float* xp = x + ((size_t)n*C0 + (size_t)g*CG)*HW;
  float* op = out + ((size_t)n*C0 + (size_t)g*CG)*HW;
  float s = 0.f, ss = 0.f;
  for (int i = threadIdx.x; i < NEL; i += 256){ float v = xp[i]; s += v; ss += v*v; }
  __shared__ float rs[256], rq[256];
  rs[threadIdx.x] = s; rq[threadIdx.x] = ss;
  __syncthreads();
  for (int o = 128; o > 0; o >>= 1){
    if (threadIdx.x < o){ rs[threadIdx.x] += rs[threadIdx.x+o]; rq[threadIdx.x] += rq[threadIdx.x+o]; }
    __syncthreads();
  }
  float mu  = rs[0] / NEL;
  float var = rq[0] / NEL - mu*mu;
  float inv = rsqrtf(var + 1e-5f);
  for (int i = threadIdx.x; i < NEL; i += 256){
    int c = g*CG + i/HW;
    op[i] = (xp[i] - mu)*inv*w[c] + b[c];
  }
}

// ---------------- weight f32 -> bf16 conversion (optional row padding) ----------------
__global__ __launch_bounds__(256) void cvt_pad_kernel(const float* __restrict__ w,
    __hip_bfloat16* __restrict__ o, int Nreal, int Npad, int K)
{
  int i = blockIdx.x*256 + threadIdx.x;
  if (i >= Npad*K) return;
  int n = i / K;
  int k = i - n*K;
  float v = (n < Nreal) ? w[(size_t)n*K + k] : 0.f;
  o[i] = __float2bfloat16(v);
}

// ---------------- frames f32 (n,c,hw) -> token-major bf16 (n*HW+hw, c) ----------------
__global__ __launch_bounds__(256) void tok_cvt_kernel(const float* __restrict__ Xg,
    __hip_bfloat16* __restrict__ X0)
{
  __shared__ float t[64][65];
  const int n = blockIdx.z, c0 = blockIdx.y*64, hw0 = blockIdx.x*64;
  const int r = threadIdx.x >> 2, sl = threadIdx.x & 3;
  size_t ibase = ((size_t)n*C0 + c0 + r)*HW + hw0 + sl*16;
  #pragma unroll
  for (int j = 0; j < 16; j++) t[r][sl*16 + j] = Xg[ibase + j];   // t[c_local][hw_local]
  __syncthreads();
  __hip_bfloat16* Orow = X0 + ((size_t)(n*HW + hw0 + r))*C0 + c0 + sl*16;
  union { uint4 u; __hip_bfloat16 h[8]; } v;
  #pragma unroll
  for (int half = 0; half < 2; half++){
    #pragma unroll
    for (int j = 0; j < 8; j++) v.h[j] = __float2bfloat16(t[sl*16 + half*8 + j][r]);
    *(uint4*)(Orow + half*8) = v.u;
  }
}

// ---------------- final: P bf16 tokens -> out f32 frames with residual ----------------
__global__ __launch_bounds__(256) void final_kernel(const __hip_bfloat16* __restrict__ P,
    const float* __restrict__ x, const float* __restrict__ gammap, float* __restrict__ out)
{
  __shared__ float t[64][65];
  const int n = blockIdx.z, c0 = blockIdx.y*64, hw0 = blockIdx.x*64;
  const int r = threadIdx.x >> 2, sl = threadIdx.x & 3;
  const __hip_bfloat16* Pr = P + ((size_t)(n*HW + hw0 + r))*C0 + c0 + sl*16;
  union { uint4 u; __hip_bfloat16 h[8]; } v;
  #pragma unroll
  for (int half = 0; half < 2; half++){
    v.u = *(const uint4*)(Pr + half*8);
    #pragma unroll
    for (int j = 0; j < 8; j++) t[sl*16 + half*8 + j][r] = __bfloat162float(v.h[j]);
  }
  __syncthreads();
  const float g = *gammap;
  size_t obase = ((size_t)n*C0 + c0 + r)*HW + hw0 + sl*16;
  #pragma unroll
  for (int j = 0; j < 16; j++)
    out[obase + j] = x[obase + j] + g*t[r][sl*16 + j];
}

// ---------------- bf16 MFMA GEMM NT: O = A(MxK) * Bw(NpadxK)^T (+bias[n]) ----------------
// 128x128 tile, BK=32, 4 waves (2x2), each wave 64x64 via 4x4 16x16x32 mfma frags.
// Staging: global_load_lds width=16, LINEAR LDS dest; XOR bank-swizzle applied to the
// per-lane GLOBAL source slot (involution), reads use the same XOR -> 0 conflicts (rule #21).
// MODE 0: bf16 out (no bias), O[m*Nreal+n], guard n<Nreal   (in_proj -> Z)
// MODE 1: bf16 out +bias, O[m*Nreal+n], guard n<Nreal       (proj_in, collapse, proj_out)
// MODE 2: bf16 out +bias, frame-tok -> seq-tok row permute  (expand -> U)
// MODE 3: bf16 out, seq-tok -> frame-tok row permute        (out_proj -> V)
template<int MODE>
__global__ __launch_bounds__(256) void mfma_nt_kernel(
    const __hip_bfloat16* __restrict__ A,   // M x K
    const __hip_bfloat16* __restrict__ Bw,  // Npad x K
    void* __restrict__ Optr,
    int Nreal, int K, int c0tok,
    const float* __restrict__ bias)
{
  __shared__ unsigned short As[128*32];
  __shared__ unsigned short Bs[128*32];
  const int tid = threadIdx.x;
  const int lane = tid & 63;
  const int wid = tid >> 6;
  const int m0 = blockIdx.y * 128;
  const int n0 = blockIdx.x * 128;

  // staging geometry: wave wid fills LDS 16B-granules [wid*128, wid*128+128)
  // granule g -> row = g>>2, lds slot = g&3; SOURCE slot = (g&3) ^ ((row>>1)&3)
  const int g0 = wid*128 + lane;
  const int g1 = g0 + 64;
  const int r0 = g0 >> 2, s0 = (g0 & 3) ^ ((r0 >> 1) & 3);
  const int r1 = g1 >> 2, s1 = (g1 & 3) ^ ((r1 >> 1) & 3);
  const __hip_bfloat16* Ag0 = A  + (size_t)(m0 + r0)*K + s0*8;
  const __hip_bfloat16* Ag1 = A  + (size_t)(m0 + r1)*K + s1*8;
  const __hip_bfloat16* Bg0 = Bw + (size_t)(n0 + r0)*K + s0*8;
  const __hip_bfloat16* Bg1 = Bw + (size_t)(n0 + r1)*K + s1*8;
  unsigned short* Ab0 = &As[wid*1024];         // wave-uniform LDS bases (+lane*16B implied)
  unsigned short* Ab1 = &As[wid*1024 + 512];
  unsigned short* Bb0 = &Bs[wid*1024];
  unsigned short* Bb1 = &Bs[wid*1024 + 512];

  // fragment read offsets (ushort units), swizzled per-row (same XOR as source)
  const int wr = wid >> 1, wc = wid & 1;
  const int fr = lane & 15, ks = lane >> 4;
  int aoff[4], boff[4];
  #pragma unroll
  for (int i = 0; i < 4; i++){
    int ra = wr*64 + i*16 + fr;
    aoff[i] = ra*32 + ((ks ^ ((ra>>1)&3))<<3);
    int rb = wc*64 + i*16 + fr;
    boff[i] = rb*32 + ((ks ^ ((rb>>1)&3))<<3);
  }

  f32x4 acc[4][4];
  #pragma unroll
  for (int mi = 0; mi < 4; mi++)
    #pragma unroll
    for (int ni = 0; ni < 4; ni++)
      acc[mi][ni] = (f32x4)(0.f);

  for (int k0 = 0; k0 < K; k0 += 32){
    __syncthreads();                       // all waves done reading prev tile
    __builtin_amdgcn_global_load_lds((glb_void*)(Ag0 + k0), (lds_void*)Ab0, 16, 0, 0);
    __builtin_amdgcn_global_load_lds((glb_void*)(Ag1 + k0), (lds_void*)Ab1, 16, 0, 0);
    __builtin_amdgcn_global_load_lds((glb_void*)(Bg0 + k0), (lds_void*)Bb0, 16, 0, 0);
    __builtin_amdgcn_global_load_lds((glb_void*)(Bg1 + k0), (lds_void*)Bb1, 16, 0, 0);
    __syncthreads();                       // drains vmcnt -> tile visible
    bf16x8 af[4], bfv[4];
    #pragma unroll
    for (int i = 0; i < 4; i++){
      af[i]  = *(const bf16x8*)&As[aoff[i]];
      bfv[i] = *(const bf16x8*)&Bs[boff[i]];
    }
    #pragma unroll
    for (int mi = 0; mi < 4; mi++)
      #pragma unroll
      for (int ni = 0; ni < 4; ni++)
        acc[mi][ni] = __builtin_amdgcn_mfma_f32_16x16x32_bf16(af[mi], bfv[ni], acc[mi][ni], 0, 0, 0);
  }

  #pragma unroll
  for (int mi = 0; mi < 4; mi++){
    #pragma unroll
    for (int ni = 0; ni < 4; ni++){
      #pragma unroll
      for (int i = 0; i < 4; i++){
        int m = m0 + wr*64 + mi*16 + (lane>>4)*4 + i;   // C/D: row=(lane>>4)*4+reg
        int n = n0 + wc*64 + ni*16 + (lane&15);          //      col=lane&15
        if (n >= Nreal) continue;
        float v = acc[mi][ni][i];
        if (MODE == 0){
          ((__hip_bfloat16*)Optr)[(size_t)m*Nreal + n] = __float2bfloat16(v);
        } else if (MODE == 1){
          ((__hip_bfloat16*)Optr)[(size_t)m*Nreal + n] = __float2bfloat16(v + bias[n]);
        } else if (MODE == 2){
          int nf = m >> 10, hw = m & (HW-1);
          int bb = nf >> 4, f = nf & (F_-1);
          size_t urow = ((size_t)((bb << 10) | hw))*F_ + f;
          ((__hip_bfloat16*)Optr)[urow*CEXP + n] = __float2bfloat16(v + bias[n]);
        } else {
          int st = c0tok + m;
          int sq = st >> 4, f = st & (F_-1);
          int bb = sq >> 10, hw = sq & (HW-1);
          size_t vrow = ((size_t)((bb << 4) | f))*HW + hw;
          ((__hip_bfloat16*)Optr)[vrow*CEXP + n] = __float2bfloat16(v);
        }
      }
    }
  }
}

// ---------------- fused conv1d + SSD + gate + RMSNorm (register x, packed y) ----------
// One block per sequence (256 threads). Thread owns cols c0=tid*4 .. c0+3 of D_INNER.
// xs[16][4] f32 stays in regs; gated y stored packed bf16 (y_pk[16][2] u32).
// LDS ~44KB -> 3 blocks/CU; VGPR ~130 (launch_bounds(256,1): no forced spill).
__global__ __launch_bounds__(256,1) void ssm_kernel(
    const __hip_bfloat16* __restrict__ Zc,   // (SEQ, F_, D_IN_PROJ) bf16 chunk
    const float* __restrict__ conv_w,  // (CONV_DIM, 4)
    const float* __restrict__ conv_b,  // (CONV_DIM)
    const float* __restrict__ dt_bias, // (NHEADS)
    const float* __restrict__ A_log,   // (NHEADS)
    const float* __restrict__ Dp,      // (NHEADS)
    const float* __restrict__ rms_w,   // (D_INNER)
    __hip_bfloat16* __restrict__ Yc)   // (SEQ, F_, D_INNER) bf16
{
  __shared__ float bc[F_][257];                 // silu(conv) of B(0..127),C(128..255)
  __shared__ __hip_bfloat16 wts[F_][F_][NHEADS];
  __shared__ float dts[F_][NHEADS];
  __shared__ float cums[F_][NHEADS];
  __shared__ float scor[F_][F_+1];
  __shared__ float red[256][17];
  __shared__ float rinv[F_];
  const int tid = threadIdx.x;
  const __hip_bfloat16* Zb = Zc + (size_t)blockIdx.x * F_ * D_IN_PROJ;
  __hip_bfloat16* Yb = Yc + (size_t)blockIdx.x * F_ * D_INNER;

  // dt = softplus(raw + dt_bias)
  {
    int t = tid >> 4, h = tid & 15;
    float v = __bfloat162float(Zb[t*D_IN_PROJ + (D_INNER + CONV_DIM) + h]) + dt_bias[h];
    dts[t][h] = (v > 20.f) ? v : log1pf(expf(v));
  }
  // B/C conv + silu
  {
    const int cc = D_INNER + tid;
    const float4 cw = *(const float4*)&conv_w[cc*4];
    const float cb = conv_b[cc];
    float r0 = 0.f, r1 = 0.f, r2 = 0.f, r3 = 0.f;
    #pragma unroll
    for (int t = 0; t < F_; t++){
      r0 = r1; r1 = r2; r2 = r3;
      r3 = __bfloat162float(Zb[t*D_IN_PROJ + D_INNER + cc]);
      float a = cb + r0*cw.x + r1*cw.y + r2*cw.z + r3*cw.w;
      bc[t][tid] = a / (1.f + expf(-a));
    }
  }
  __syncthreads();
  // cumulative dt*A per head
  if (tid < NHEADS){
    float A = -expf(A_log[tid]);
    float c = 0.f;
    for (int t = 0; t < F_; t++){ c += dts[t][tid]*A; cums[t][tid] = c; }
  }
  // scores[t][s] = C[t] . B[s]
  {
    int t = tid >> 4, s = tid & 15;
    float acc = 0.f;
    #pragma unroll 8
    for (int n = 0; n < D_STATE; n++)
      acc += bc[t][128 + n] * bc[s][n];
    scor[t][s] = acc;
  }
  __syncthreads();
  // wts[t][s][h] (bf16)
  #pragma unroll
  for (int rep = 0; rep < 16; rep++){
    int i = rep*256 + tid;
    int h = i & 15, s = (i >> 4) & 15, t = i >> 8;
    float v = 0.f;
    if (s <= t) v = scor[t][s] * expf(cums[t][h] - cums[s][h]) * dts[s][h];
    wts[t][s][h] = __float2bfloat16(v);
  }
  __syncthreads();

  // ---- register-resident x path ----
  const int c0 = tid*4;
  const int h  = tid >> 4;
  const float Dh = Dp[h];
  const float4 cw0 = *(const float4*)&conv_w[(c0+0)*4];
  const float4 cw1 = *(const float4*)&conv_w[(c0+1)*4];
  const float4 cw2 = *(const float4*)&conv_w[(c0+2)*4];
  const float4 cw3 = *(const float4*)&conv_w[(c0+3)*4];
  const float4 cb4 = *(const float4*)&conv_b[c0];

  // conv1d + silu -> xs[16][4] (static indices, stays in VGPRs)
  float xs[F_][4];
  {
    float w0[4] = {0,0,0,0}, w1[4] = {0,0,0,0}, w2[4] = {0,0,0,0}, w3[4] = {0,0,0,0};
    #pragma unroll
    for (int s = 0; s < F_; s++){
      union { ushort4 u; __hip_bfloat16 hh[4]; } rv;
      rv.u = *(const ushort4*)&Zb[s*D_IN_PROJ + D_INNER + c0];
      #pragma unroll
      for (int j = 0; j < 4; j++){ w0[j]=w1[j]; w1[j]=w2[j]; w2[j]=w3[j]; }
      w3[0]=__bfloat162float(rv.hh[0]); w3[1]=__bfloat162float(rv.hh[1]);
      w3[2]=__bfloat162float(rv.hh[2]); w3[3]=__bfloat162float(rv.hh[3]);
      float a;
      a = cb4.x + w0[0]*cw0.x + w1[0]*cw0.y + w2[0]*cw0.z + w3[0]*cw0.w; xs[s][0] = a/(1.f+expf(-a));
      a = cb4.y + w0[1]*cw1.x + w1[1]*cw1.y + w2[1]*cw1.z + w3[1]*cw1.w; xs[s][1] = a/(1.f+expf(-a));
      a = cb4.z + w0[2]*cw2.x + w1[2]*cw2.y + w2[2]*cw2.z + w3[2]*cw2.w; xs[s][2] = a/(1.f+expf(-a));
      a = cb4.w + w0[3]*cw3.x + w1[3]*cw3.y + w2[3]*cw3.z + w3[3]*cw3.w; xs[s][3] = a/(1.f+expf(-a));
    }
  }

  // per-t: SSD sum (f32), gate, square-partial, pack to bf16 pair regs
  unsigned int y_pk[F_][2];
  #pragma unroll
  for (int t = 0; t < F_; t++){
    float y0 = Dh*xs[t][0], y1 = Dh*xs[t][1], y2 = Dh*xs[t][2], y3 = Dh*xs[t][3];
    #pragma unroll
    for (int s = 0; s < F_; s++){
      if (s > t) continue;                      // compile-time eliminated
      float wv = __bfloat162float(wts[t][s][h]);
      y0 += wv*xs[s][0]; y1 += wv*xs[s][1];
      y2 += wv*xs[s][2]; y3 += wv*xs[s][3];
    }
    union { ushort4 u; __hip_bfloat16 hh[4]; } zv;
    zv.u = *(const ushort4*)&Zb[t*D_IN_PROJ + c0];
    float z0 = __bfloat162float(zv.hh[0]), z1 = __bfloat162float(zv.hh[1]);
    float z2 = __bfloat162float(zv.hh[2]), z3 = __bfloat162float(zv.hh[3]);
    y0 *= z0/(1.f+expf(-z0)); y1 *= z1/(1.f+expf(-z1));
    y2 *= z2/(1.f+expf(-z2)); y3 *= z3/(1.f+expf(-z3));
    red[tid][t] = y0*y0 + y1*y1 + y2*y2 + y3*y3;
    union { unsigned int u; unsigned short s2[2]; } p0, p1;
    // round-to-nearest bf16 pack
    __hip_bfloat16 b0 = __float2bfloat16(y0), b1 = __float2bfloat16(y1);
    __hip_bfloat16 b2 = __float2bfloat16(y2), b3 = __float2bfloat16(y3);
    p0.s2[0] = *(unsigned short*)&b0; p0.s2[1] = *(unsigned short*)&b1;
    p1.s2[0] = *(unsigned short*)&b2; p1.s2[1] = *(unsigned short*)&b3;
    y_pk[t][0] = p0.u; y_pk[t][1] = p1.u;
  }
  __syncthreads();
  // reduce 256 -> 16 -> 1 per t
  {
    int t = tid >> 4, seg = tid & 15;
    float s2 = 0.f;
    #pragma unroll
    for (int j = 0; j < 16; j++) s2 += red[seg*16 + j][t];
    scor[t][seg] = s2;
  }
  __syncthreads();
  if (tid < F_){
    float s = 0.f;
    #pragma unroll
    for (int j = 0; j < 16; j++) s += scor[tid][j];
    rinv[tid] = rsqrtf(s / D_INNER + 1e-5f);
  }
  __syncthreads();
  // unpack, normalize, write bf16
  const float4 rw = *(const float4*)&rms_w[c0];
  #pragma unroll
  for (int t = 0; t < F_; t++){
    float ri = rinv[t];
    union { unsigned int u; unsigned short s2[2]; } p0, p1;
    p0.u = y_pk[t][0]; p1.u = y_pk[t][1];
    union { unsigned int u; float f; } f0, f1, f2, f3;
    f0.u = (unsigned int)p0.s2[0] << 16; f1.u = (unsigned int)p0.s2[1] << 16;
    f2.u = (unsigned int)p1.s2[0] << 16; f3.u = (unsigned int)p1.s2[1] << 16;
    union { ushort4 u; __hip_bfloat16 hh[4]; } ov;
    ov.hh[0] = __float2bfloat16(f0.f*ri*rw.x);
    ov.hh[1] = __float2bfloat16(f1.f*ri*rw.y);
    ov.hh[2] = __float2bfloat16(f2.f*ri*rw.z);
    ov.hh[3] = __float2bfloat16(f3.f*ri*rw.w);
    *(ushort4*)&Yb[t*D_INNER + c0] = ov.u;
  }
}

// ---------------- launcher ----------------
// workspace (float offsets), peak ~169 MiB:
//   Xg  f32  [0, 10485760)  -> V bf16 (reuse)
//   X0  bf16 [10485760, 15728640) -> C2 (reuse)
//   X1  bf16 [15728640, 20971520) -> P  (reuse)
//   U   bf16 [20971520, 29360128)
//   weights bf16 [29360128, 30547968)
//   Z   bf16 [30547968, 40050688)   8192 x 2320
//   Ycb bf16 [40050688, 44244992)   8192 x 1024
extern "C" void kernel_launch(void* const* d_in, const int* in_sizes, int n_in,
                              void* d_out, int out_size, void* d_ws, size_t ws_size,
                              hipStream_t stream)
{
  const float* x         = (const float*)d_in[0];
  const float* norm_w    = (const float*)d_in[1];
  const float* norm_b    = (const float*)d_in[2];
  const float* proj_in_w = (const float*)d_in[3];
  const float* proj_in_b = (const float*)d_in[4];
  const float* expand_w  = (const float*)d_in[5];
  const float* expand_b  = (const float*)d_in[6];
  const float* in_proj_w = (const float*)d_in[7];
  const float* conv_w    = (const float*)d_in[8];
  const float* conv_b    = (const float*)d_in[9];
  const float* dt_bias   = (const float*)d_in[10];
  const float* A_log     = (const float*)d_in[11];
  const float* Dvec      = (const float*)d_in[12];
  const float* rms_w     = (const float*)d_in[13];
  const float* out_proj_w= (const float*)d_in[14];
  const float* collapse_w= (const float*)d_in[15];
  const float* collapse_b= (const float*)d_in[16];
  const float* proj_out_w= (const float*)d_in[17];
  const float* proj_out_b= (const float*)d_in[18];
  const float* gamma     = (const float*)d_in[19];
  float* out = (float*)d_out;

  float* WS = (float*)d_ws;
  float*          Xg  = WS;
  __hip_bfloat16* V   = (__hip_bfloat16*)WS;                   // reuses Xg
  __hip_bfloat16* X0  = (__hip_bfloat16*)(WS + 10485760);
  __hip_bfloat16* C2  = (__hip_bfloat16*)(WS + 10485760);      // reuses X0
  __hip_bfloat16* X1  = (__hip_bfloat16*)(WS + 15728640);
  __hip_bfloat16* P   = (__hip_bfloat16*)(WS + 15728640);      // reuses X1
  __hip_bfloat16* U   = (__hip_bfloat16*)(WS + 20971520);
  __hip_bfloat16* Wb  = (__hip_bfloat16*)(WS + 29360128);
  __hip_bfloat16* Wob = (__hip_bfloat16*)(WS + 29982720);
  __hip_bfloat16* Wpb = (__hip_bfloat16*)(WS + 30244864);
  __hip_bfloat16* Web = (__hip_bfloat16*)(WS + 30306304);
  __hip_bfloat16* Wcb = (__hip_bfloat16*)(WS + 30388224);
  __hip_bfloat16* Wqb = (__hip_bfloat16*)(WS + 30486528);
  __hip_bfloat16* Z   = (__hip_bfloat16*)(WS + 30547968);
  __hip_bfloat16* Ycb = (__hip_bfloat16*)(WS + 40050688);

  // 0) weight conversions
  cvt_pad_kernel<<<(NPAD*CEXP+255)/256, 256, 0, stream>>>(in_proj_w, Wb, D_IN_PROJ, NPAD, CEXP);
  cvt_pad_kernel<<<(CEXP*D_INNER+255)/256, 256, 0, stream>>>(out_proj_w, Wob, CEXP, CEXP, D_INNER);
  cvt_pad_kernel<<<(C0PAD*C0+255)/256, 256, 0, stream>>>(proj_in_w, Wpb, C0, C0PAD, C0);
  cvt_pad_kernel<<<(CEXP*C0+255)/256, 256, 0, stream>>>(expand_w, Web, CEXP, CEXP, C0);
  cvt_pad_kernel<<<(C0PAD*CEXP+255)/256, 256, 0, stream>>>(collapse_w, Wcb, C0, C0PAD, CEXP);
  cvt_pad_kernel<<<(C0PAD*C0+255)/256, 256, 0, stream>>>(proj_out_w, Wqb, C0, C0PAD, C0);
  // 1) GroupNorm
  gn_kernel<<<dim3(GROUPS, NB), 256, 0, stream>>>(x, norm_w, norm_b, Xg);
  // 2) frames -> token-major bf16
  tok_cvt_kernel<<<dim3(HW/64, C0/64, NB), 256, 0, stream>>>(Xg, X0);
  // 3) proj_in
  mfma_nt_kernel<1><<<dim3(C0PAD/128, NTOK/128), 256, 0, stream>>>(
      X0, Wpb, X1, C0, C0, 0, proj_in_b);
  // 4) expand, rows permuted frame->seq
  mfma_nt_kernel<2><<<dim3(CEXP/128, NTOK/128), 256, 0, stream>>>(
      X1, Web, U, CEXP, C0, 0, expand_b);
  // 5) chunked mamba
  for (int c = 0; c < NCHUNK; c++){
    const __hip_bfloat16* Uc = U + (size_t)c*TOK_PER*CEXP;
    mfma_nt_kernel<0><<<dim3(NPAD/128, TOK_PER/128), 256, 0, stream>>>(
        Uc, Wb, Z, D_IN_PROJ, CEXP, 0, nullptr);
    ssm_kernel<<<SEQ_PER, 256, 0, stream>>>(
        Z, conv_w, conv_b, dt_bias, A_log, Dvec, rms_w, Ycb);
    mfma_nt_kernel<3><<<dim3(CEXP/128, TOK_PER/128), 256, 0, stream>>>(
        Ycb, Wob, V, CEXP, D_INNER, c*TOK_PER, nullptr);
  }
  // 6) collapse (+bias)
  mfma_nt_kernel<1><<<dim3(C0PAD/128, NTOK/128), 256, 0, stream>>>(
      V, Wcb, C2, C0, CEXP, 0, collapse_b);
  // 7) proj_out (+bias)
  mfma_nt_kernel<1><<<dim3(C0PAD/128, NTOK/128), 256, 0, stream>>>(
      C2, Wqb, P, C0, C0, 0, proj_out_b);
  // 8) final residual transpose
  final_kernel<<<dim3(HW/64, C0/64, NB), 256, 0, stream>>>(P, x, gamma, out);
}

// Round 10
// 666.538 us; speedup vs baseline: 1.0305x; 1.0305x over previous
//
#include <hip/hip_runtime.h>
#include <hip/hip_bf16.h>

// ---------------- problem constants ----------------
#define B_ 2
#define F_ 16
#define Hs 32
#define Ws 32
#define C0 320
#define CEXP 512
#define D_INNER 1024
#define NHEADS 16
#define HEADDIM 64
#define D_STATE 128
#define D_CONV 4
#define CONV_DIM (D_INNER + 2*D_STATE)              // 1280
#define D_IN_PROJ (2*D_INNER + 2*D_STATE + NHEADS)  // 2320
#define NPAD 2432                                   // 19*128 padded in_proj rows
#define C0PAD 384                                   // 3*128 padded 320-row weights
#define GROUPS 32
#define NB (B_*F_)        // 32 frames
#define HW (Hs*Ws)        // 1024 spatial
#define NSEQ (B_*HW)      // 2048 sequences
#define NTOK (NSEQ*F_)    // 32768 tokens
#define NCHUNK 4
#define SEQ_PER (NSEQ/NCHUNK)   // 512
#define TOK_PER (SEQ_PER*F_)    // 8192

typedef __bf16 bf16x8 __attribute__((ext_vector_type(8)));
typedef float f32x4 __attribute__((ext_vector_type(4)));
typedef __attribute__((address_space(3))) void lds_void;
typedef const __attribute__((address_space(1))) void glb_void;

// ---------------- GroupNorm (f32 frames) ----------------
__global__ __launch_bounds__(256) void gn_kernel(const float* __restrict__ x,
    const float* __restrict__ w, const float* __restrict__ b, float* __restrict__ out)
{
  const int CG = C0/GROUPS;            // 10
  const int NEL = CG*HW;               // 10240
  int g = blockIdx.x, n = blockIdx.y;
  const float* xp = x + ((size_t)n*C0 + (size_t)g*CG)*HW;
  float* op = out + ((size_t)n*C0 + (size_t)g*CG)*HW;
  float s = 0.f, ss = 0.f;
  for (int i = threadIdx.x; i < NEL; i += 256){ float v = xp[i]; s += v; ss += v*v; }
  __shared__ float rs[256], rq[256];
  rs[threadIdx.x] = s; rq[threadIdx.x] = ss;
  __syncthreads();
  for (int o = 128; o > 0; o >>= 1){
    if (threadIdx.x < o){ rs[threadIdx.x] += rs[threadIdx.x+o]; rq[threadIdx.x] += rq[threadIdx.x+o]; }
    __syncthreads();
  }
  float mu  = rs[0] / NEL;
  float var = rq[0] / NEL - mu*mu;
  float inv = rsqrtf(var + 1e-5f);
  for (int i = threadIdx.x; i < NEL; i += 256){
    int c = g*CG + i/HW;
    op[i] = (xp[i] - mu)*inv*w[c] + b[c];
  }
}

// ---------------- weight f32 -> bf16 conversion (optional row padding) ----------------
__global__ __launch_bounds__(256) void cvt_pad_kernel(const float* __restrict__ w,
    __hip_bfloat16* __restrict__ o, int Nreal, int Npad, int K)
{
  int i = blockIdx.x*256 + threadIdx.x;
  if (i >= Npad*K) return;
  int n = i / K;
  int k = i - n*K;
  float v = (n < Nreal) ? w[(size_t)n*K + k] : 0.f;
  o[i] = __float2bfloat16(v);
}

// ---------------- frames f32 (n,c,hw) -> token-major bf16 (n*HW+hw, c) ----------------
__global__ __launch_bounds__(256) void tok_cvt_kernel(const float* __restrict__ Xg,
    __hip_bfloat16* __restrict__ X0)
{
  __shared__ float t[64][65];
  const int n = blockIdx.z, c0 = blockIdx.y*64, hw0 = blockIdx.x*64;
  const int r = threadIdx.x >> 2, sl = threadIdx.x & 3;
  size_t ibase = ((size_t)n*C0 + c0 + r)*HW + hw0 + sl*16;
  #pragma unroll
  for (int j = 0; j < 16; j++) t[r][sl*16 + j] = Xg[ibase + j];   // t[c_local][hw_local]
  __syncthreads();
  __hip_bfloat16* Orow = X0 + ((size_t)(n*HW + hw0 + r))*C0 + c0 + sl*16;
  union { uint4 u; __hip_bfloat16 h[8]; } v;
  #pragma unroll
  for (int half = 0; half < 2; half++){
    #pragma unroll
    for (int j = 0; j < 8; j++) v.h[j] = __float2bfloat16(t[sl*16 + half*8 + j][r]);
    *(uint4*)(Orow + half*8) = v.u;
  }
}

// ---------------- final: P bf16 tokens -> out f32 frames with residual ----------------
__global__ __launch_bounds__(256) void final_kernel(const __hip_bfloat16* __restrict__ P,
    const float* __restrict__ x, const float* __restrict__ gammap, float* __restrict__ out)
{
  __shared__ float t[64][65];
  const int n = blockIdx.z, c0 = blockIdx.y*64, hw0 = blockIdx.x*64;
  const int r = threadIdx.x >> 2, sl = threadIdx.x & 3;
  const __hip_bfloat16* Pr = P + ((size_t)(n*HW + hw0 + r))*C0 + c0 + sl*16;
  union { uint4 u; __hip_bfloat16 h[8]; } v;
  #pragma unroll
  for (int half = 0; half < 2; half++){
    v.u = *(const uint4*)(Pr + half*8);
    #pragma unroll
    for (int j = 0; j < 8; j++) t[sl*16 + half*8 + j][r] = __bfloat162float(v.h[j]);
  }
  __syncthreads();
  const float g = *gammap;
  size_t obase = ((size_t)n*C0 + c0 + r)*HW + hw0 + sl*16;
  #pragma unroll
  for (int j = 0; j < 16; j++)
    out[obase + j] = x[obase + j] + g*t[r][sl*16 + j];
}

// ---------------- bf16 MFMA GEMM NT: O = A(MxK) * Bw(NpadxK)^T (+bias[n]) ----------------
// 128x128 tile, BK=32, 4 waves (2x2), each wave 64x64 via 4x4 16x16x32 mfma frags.
// Staging: global_load_lds width=16, LINEAR LDS dest; XOR bank-swizzle applied to the
// per-lane GLOBAL source slot (involution), reads use the same XOR -> 0 conflicts (rule #21).
// MODE 0: bf16 out (no bias), O[m*Nreal+n], guard n<Nreal   (in_proj -> Z)
// MODE 1: bf16 out +bias, O[m*Nreal+n], guard n<Nreal       (proj_in, collapse, proj_out)
// MODE 2: bf16 out +bias, frame-tok -> seq-tok row permute  (expand -> U)
// MODE 3: bf16 out, seq-tok -> frame-tok row permute        (out_proj -> V)
template<int MODE>
__global__ __launch_bounds__(256) void mfma_nt_kernel(
    const __hip_bfloat16* __restrict__ A,   // M x K
    const __hip_bfloat16* __restrict__ Bw,  // Npad x K
    void* __restrict__ Optr,
    int Nreal, int K, int c0tok,
    const float* __restrict__ bias)
{
  __shared__ unsigned short As[128*32];
  __shared__ unsigned short Bs[128*32];
  const int tid = threadIdx.x;
  const int lane = tid & 63;
  const int wid = tid >> 6;
  const int m0 = blockIdx.y * 128;
  const int n0 = blockIdx.x * 128;

  // staging geometry: wave wid fills LDS 16B-granules [wid*128, wid*128+128)
  // granule g -> row = g>>2, lds slot = g&3; SOURCE slot = (g&3) ^ ((row>>1)&3)
  const int g0 = wid*128 + lane;
  const int g1 = g0 + 64;
  const int r0 = g0 >> 2, s0 = (g0 & 3) ^ ((r0 >> 1) & 3);
  const int r1 = g1 >> 2, s1 = (g1 & 3) ^ ((r1 >> 1) & 3);
  const __hip_bfloat16* Ag0 = A  + (size_t)(m0 + r0)*K + s0*8;
  const __hip_bfloat16* Ag1 = A  + (size_t)(m0 + r1)*K + s1*8;
  const __hip_bfloat16* Bg0 = Bw + (size_t)(n0 + r0)*K + s0*8;
  const __hip_bfloat16* Bg1 = Bw + (size_t)(n0 + r1)*K + s1*8;
  unsigned short* Ab0 = &As[wid*1024];         // wave-uniform LDS bases (+lane*16B implied)
  unsigned short* Ab1 = &As[wid*1024 + 512];
  unsigned short* Bb0 = &Bs[wid*1024];
  unsigned short* Bb1 = &Bs[wid*1024 + 512];

  // fragment read offsets (ushort units), swizzled per-row (same XOR as source)
  const int wr = wid >> 1, wc = wid & 1;
  const int fr = lane & 15, ks = lane >> 4;
  int aoff[4], boff[4];
  #pragma unroll
  for (int i = 0; i < 4; i++){
    int ra = wr*64 + i*16 + fr;
    aoff[i] = ra*32 + ((ks ^ ((ra>>1)&3))<<3);
    int rb = wc*64 + i*16 + fr;
    boff[i] = rb*32 + ((ks ^ ((rb>>1)&3))<<3);
  }

  f32x4 acc[4][4];
  #pragma unroll
  for (int mi = 0; mi < 4; mi++)
    #pragma unroll
    for (int ni = 0; ni < 4; ni++)
      acc[mi][ni] = (f32x4)(0.f);

  for (int k0 = 0; k0 < K; k0 += 32){
    __syncthreads();                       // all waves done reading prev tile
    __builtin_amdgcn_global_load_lds((glb_void*)(Ag0 + k0), (lds_void*)Ab0, 16, 0, 0);
    __builtin_amdgcn_global_load_lds((glb_void*)(Ag1 + k0), (lds_void*)Ab1, 16, 0, 0);
    __builtin_amdgcn_global_load_lds((glb_void*)(Bg0 + k0), (lds_void*)Bb0, 16, 0, 0);
    __builtin_amdgcn_global_load_lds((glb_void*)(Bg1 + k0), (lds_void*)Bb1, 16, 0, 0);
    __syncthreads();                       // drains vmcnt -> tile visible
    bf16x8 af[4], bfv[4];
    #pragma unroll
    for (int i = 0; i < 4; i++){
      af[i]  = *(const bf16x8*)&As[aoff[i]];
      bfv[i] = *(const bf16x8*)&Bs[boff[i]];
    }
    #pragma unroll
    for (int mi = 0; mi < 4; mi++)
      #pragma unroll
      for (int ni = 0; ni < 4; ni++)
        acc[mi][ni] = __builtin_amdgcn_mfma_f32_16x16x32_bf16(af[mi], bfv[ni], acc[mi][ni], 0, 0, 0);
  }

  #pragma unroll
  for (int mi = 0; mi < 4; mi++){
    #pragma unroll
    for (int ni = 0; ni < 4; ni++){
      #pragma unroll
      for (int i = 0; i < 4; i++){
        int m = m0 + wr*64 + mi*16 + (lane>>4)*4 + i;   // C/D: row=(lane>>4)*4+reg
        int n = n0 + wc*64 + ni*16 + (lane&15);          //      col=lane&15
        if (n >= Nreal) continue;
        float v = acc[mi][ni][i];
        if (MODE == 0){
          ((__hip_bfloat16*)Optr)[(size_t)m*Nreal + n] = __float2bfloat16(v);
        } else if (MODE == 1){
          ((__hip_bfloat16*)Optr)[(size_t)m*Nreal + n] = __float2bfloat16(v + bias[n]);
        } else if (MODE == 2){
          int nf = m >> 10, hw = m & (HW-1);
          int bb = nf >> 4, f = nf & (F_-1);
          size_t urow = ((size_t)((bb << 10) | hw))*F_ + f;
          ((__hip_bfloat16*)Optr)[urow*CEXP + n] = __float2bfloat16(v + bias[n]);
        } else {
          int st = c0tok + m;
          int sq = st >> 4, f = st & (F_-1);
          int bb = sq >> 10, hw = sq & (HW-1);
          size_t vrow = ((size_t)((bb << 4) | f))*HW + hw;
          ((__hip_bfloat16*)Optr)[vrow*CEXP + n] = __float2bfloat16(v);
        }
      }
    }
  }
}

// ---------------- fused conv1d + SSD + gate + RMSNorm (512 threads, 2 cols/thread) ----
// One block per sequence. 8 waves/block -> 16 waves/CU at grid 512 (2 blocks/CU).
// Halved per-thread serial chains vs 256-thread version; RMS reduce via shfl_xor.
__global__ __launch_bounds__(512,1) void ssm_kernel(
    const __hip_bfloat16* __restrict__ Zc,   // (SEQ, F_, D_IN_PROJ) bf16 chunk
    const float* __restrict__ conv_w,  // (CONV_DIM, 4)
    const float* __restrict__ conv_b,  // (CONV_DIM)
    const float* __restrict__ dt_bias, // (NHEADS)
    const float* __restrict__ A_log,   // (NHEADS)
    const float* __restrict__ Dp,      // (NHEADS)
    const float* __restrict__ rms_w,   // (D_INNER)
    __hip_bfloat16* __restrict__ Yc)   // (SEQ, F_, D_INNER) bf16
{
  __shared__ float bc[F_][257];                 // silu(conv) of B(0..127),C(128..255)
  __shared__ __hip_bfloat16 wts[F_][F_][NHEADS];
  __shared__ float dts[F_][NHEADS];
  __shared__ float cums[F_][NHEADS];
  __shared__ float scor[F_][F_+1];
  __shared__ float wred[8][F_+1];               // per-wave RMS partials
  __shared__ float rinv[F_];
  const int tid = threadIdx.x;
  const int lane = tid & 63, wid = tid >> 6;
  const __hip_bfloat16* Zb = Zc + (size_t)blockIdx.x * F_ * D_IN_PROJ;
  __hip_bfloat16* Yb = Yc + (size_t)blockIdx.x * F_ * D_INNER;

  // dt = softplus(raw + dt_bias)   [threads 0..255]
  if (tid < 256){
    int t = tid >> 4, h = tid & 15;
    float v = __bfloat162float(Zb[t*D_IN_PROJ + (D_INNER + CONV_DIM) + h]) + dt_bias[h];
    dts[t][h] = (v > 20.f) ? v : log1pf(expf(v));
  }
  // B/C conv + silu                [threads 0..255]
  if (tid < 256){
    const int cc = D_INNER + tid;
    const float4 cw = *(const float4*)&conv_w[cc*4];
    const float cb = conv_b[cc];
    float r0 = 0.f, r1 = 0.f, r2 = 0.f, r3 = 0.f;
    #pragma unroll
    for (int t = 0; t < F_; t++){
      r0 = r1; r1 = r2; r2 = r3;
      r3 = __bfloat162float(Zb[t*D_IN_PROJ + D_INNER + tid]);
      float a = cb + r0*cw.x + r1*cw.y + r2*cw.z + r3*cw.w;
      bc[t][tid] = a / (1.f + expf(-a));
    }
  }
  __syncthreads();
  // cumulative dt*A per head
  if (tid < NHEADS){
    float A = -expf(A_log[tid]);
    float c = 0.f;
    for (int t = 0; t < F_; t++){ c += dts[t][tid]*A; cums[t][tid] = c; }
  }
  // scores[t][s] = C[t] . B[s]     [threads 0..255]
  if (tid < 256){
    int t = tid >> 4, s = tid & 15;
    float acc = 0.f;
    #pragma unroll 8
    for (int n = 0; n < D_STATE; n++)
      acc += bc[t][128 + n] * bc[s][n];
    scor[t][s] = acc;
  }
  __syncthreads();
  // wts[t][s][h] (bf16)            [all 512 threads, 8 reps]
  #pragma unroll
  for (int rep = 0; rep < 8; rep++){
    int i = rep*512 + tid;
    int h = i & 15, s = (i >> 4) & 15, t = i >> 8;
    float v = 0.f;
    if (s <= t) v = scor[t][s] * expf(cums[t][h] - cums[s][h]) * dts[s][h];
    wts[t][s][h] = __float2bfloat16(v);
  }
  __syncthreads();

  // ---- register-resident x path: 2 cols/thread ----
  const int c0 = tid*2;
  const int h  = c0 >> 6;
  const float Dh = Dp[h];
  const float4 cw0 = *(const float4*)&conv_w[(c0+0)*4];
  const float4 cw1 = *(const float4*)&conv_w[(c0+1)*4];
  const float2 cb2 = *(const float2*)&conv_b[c0];

  // conv1d + silu -> xs[16][2] (static indices, stays in VGPRs)
  float xs[F_][2];
  {
    float w0[2] = {0,0}, w1[2] = {0,0}, w2[2] = {0,0}, w3[2] = {0,0};
    #pragma unroll
    for (int s = 0; s < F_; s++){
      union { unsigned int u; __hip_bfloat16 hh[2]; } rv;
      rv.u = *(const unsigned int*)&Zb[s*D_IN_PROJ + D_INNER + c0];
      w0[0]=w1[0]; w1[0]=w2[0]; w2[0]=w3[0];
      w0[1]=w1[1]; w1[1]=w2[1]; w2[1]=w3[1];
      w3[0]=__bfloat162float(rv.hh[0]); w3[1]=__bfloat162float(rv.hh[1]);
      float a;
      a = cb2.x + w0[0]*cw0.x + w1[0]*cw0.y + w2[0]*cw0.z + w3[0]*cw0.w; xs[s][0] = a/(1.f+expf(-a));
      a = cb2.y + w0[1]*cw1.x + w1[1]*cw1.y + w2[1]*cw1.z + w3[1]*cw1.w; xs[s][1] = a/(1.f+expf(-a));
    }
  }

  // per-t: SSD sum (f32), gate, wave-reduce square-partial, pack to bf16 pair reg
  unsigned int y_pk[F_];
  #pragma unroll
  for (int t = 0; t < F_; t++){
    float y0 = Dh*xs[t][0], y1 = Dh*xs[t][1];
    #pragma unroll
    for (int s = 0; s < F_; s++){
      if (s > t) continue;                      // compile-time eliminated
      float wv = __bfloat162float(wts[t][s][h]);
      y0 += wv*xs[s][0]; y1 += wv*xs[s][1];
    }
    union { unsigned int u; __hip_bfloat16 hh[2]; } zv;
    zv.u = *(const unsigned int*)&Zb[t*D_IN_PROJ + c0];
    float z0 = __bfloat162float(zv.hh[0]), z1 = __bfloat162float(zv.hh[1]);
    y0 *= z0/(1.f+expf(-z0)); y1 *= z1/(1.f+expf(-z1));
    // wave butterfly reduce of squared partials
    float p = y0*y0 + y1*y1;
    p += __shfl_xor(p, 1);  p += __shfl_xor(p, 2);  p += __shfl_xor(p, 4);
    p += __shfl_xor(p, 8);  p += __shfl_xor(p, 16); p += __shfl_xor(p, 32);
    if (lane == 0) wred[wid][t] = p;
    // pack to bf16 pair
    __hip_bfloat16 b0 = __float2bfloat16(y0), b1 = __float2bfloat16(y1);
    union { unsigned int u; unsigned short s2[2]; } pk;
    pk.s2[0] = *(unsigned short*)&b0; pk.s2[1] = *(unsigned short*)&b1;
    y_pk[t] = pk.u;
  }
  __syncthreads();
  if (tid < F_){
    float s = 0.f;
    #pragma unroll
    for (int w = 0; w < 8; w++) s += wred[w][tid];
    rinv[tid] = rsqrtf(s / D_INNER + 1e-5f);
  }
  __syncthreads();
  // unpack, normalize, write bf16
  const float2 rw = *(const float2*)&rms_w[c0];
  #pragma unroll
  for (int t = 0; t < F_; t++){
    float ri = rinv[t];
    union { unsigned int u; unsigned short s2[2]; } pk;
    pk.u = y_pk[t];
    union { unsigned int u; float f; } f0, f1;
    f0.u = (unsigned int)pk.s2[0] << 16; f1.u = (unsigned int)pk.s2[1] << 16;
    union { unsigned int u; __hip_bfloat16 hh[2]; } ov;
    __hip_bfloat16 o0 = __float2bfloat16(f0.f*ri*rw.x);
    __hip_bfloat16 o1 = __float2bfloat16(f1.f*ri*rw.y);
    ov.hh[0] = o0; ov.hh[1] = o1;
    *(unsigned int*)&Yb[t*D_INNER + c0] = ov.u;
  }
}

// ---------------- launcher ----------------
// workspace (float offsets), peak ~169 MiB:
//   Xg  f32  [0, 10485760)  -> V bf16 (reuse)
//   X0  bf16 [10485760, 15728640) -> C2 (reuse)
//   X1  bf16 [15728640, 20971520) -> P  (reuse)
//   U   bf16 [20971520, 29360128)
//   weights bf16 [29360128, 30547968)
//   Z   bf16 [30547968, 40050688)   8192 x 2320
//   Ycb bf16 [40050688, 44244992)   8192 x 1024
extern "C" void kernel_launch(void* const* d_in, const int* in_sizes, int n_in,
                              void* d_out, int out_size, void* d_ws, size_t ws_size,
                              hipStream_t stream)
{
  const float* x         = (const float*)d_in[0];
  const float* norm_w    = (const float*)d_in[1];
  const float* norm_b    = (const float*)d_in[2];
  const float* proj_in_w = (const float*)d_in[3];
  const float* proj_in_b = (const float*)d_in[4];
  const float* expand_w  = (const float*)d_in[5];
  const float* expand_b  = (const float*)d_in[6];
  const float* in_proj_w = (const float*)d_in[7];
  const float* conv_w    = (const float*)d_in[8];
  const float* conv_b    = (const float*)d_in[9];
  const float* dt_bias   = (const float*)d_in[10];
  const float* A_log     = (const float*)d_in[11];
  const float* Dvec      = (const float*)d_in[12];
  const float* rms_w     = (const float*)d_in[13];
  const float* out_proj_w= (const float*)d_in[14];
  const float* collapse_w= (const float*)d_in[15];
  const float* collapse_b= (const float*)d_in[16];
  const float* proj_out_w= (const float*)d_in[17];
  const float* proj_out_b= (const float*)d_in[18];
  const float* gamma     = (const float*)d_in[19];
  float* out = (float*)d_out;

  float* WS = (float*)d_ws;
  float*          Xg  = WS;
  __hip_bfloat16* V   = (__hip_bfloat16*)WS;                   // reuses Xg
  __hip_bfloat16* X0  = (__hip_bfloat16*)(WS + 10485760);
  __hip_bfloat16* C2  = (__hip_bfloat16*)(WS + 10485760);      // reuses X0
  __hip_bfloat16* X1  = (__hip_bfloat16*)(WS + 15728640);
  __hip_bfloat16* P   = (__hip_bfloat16*)(WS + 15728640);      // reuses X1
  __hip_bfloat16* U   = (__hip_bfloat16*)(WS + 20971520);
  __hip_bfloat16* Wb  = (__hip_bfloat16*)(WS + 29360128);
  __hip_bfloat16* Wob = (__hip_bfloat16*)(WS + 29982720);
  __hip_bfloat16* Wpb = (__hip_bfloat16*)(WS + 30244864);
  __hip_bfloat16* Web = (__hip_bfloat16*)(WS + 30306304);
  __hip_bfloat16* Wcb = (__hip_bfloat16*)(WS + 30388224);
  __hip_bfloat16* Wqb = (__hip_bfloat16*)(WS + 30486528);
  __hip_bfloat16* Z   = (__hip_bfloat16*)(WS + 30547968);
  __hip_bfloat16* Ycb = (__hip_bfloat16*)(WS + 40050688);

  // 0) weight conversions
  cvt_pad_kernel<<<(NPAD*CEXP+255)/256, 256, 0, stream>>>(in_proj_w, Wb, D_IN_PROJ, NPAD, CEXP);
  cvt_pad_kernel<<<(CEXP*D_INNER+255)/256, 256, 0, stream>>>(out_proj_w, Wob, CEXP, CEXP, D_INNER);
  cvt_pad_kernel<<<(C0PAD*C0+255)/256, 256, 0, stream>>>(proj_in_w, Wpb, C0, C0PAD, C0);
  cvt_pad_kernel<<<(CEXP*C0+255)/256, 256, 0, stream>>>(expand_w, Web, CEXP, CEXP, C0);
  cvt_pad_kernel<<<(C0PAD*CEXP+255)/256, 256, 0, stream>>>(collapse_w, Wcb, C0, C0PAD, CEXP);
  cvt_pad_kernel<<<(C0PAD*C0+255)/256, 256, 0, stream>>>(proj_out_w, Wqb, C0, C0PAD, C0);
  // 1) GroupNorm
  gn_kernel<<<dim3(GROUPS, NB), 256, 0, stream>>>(x, norm_w, norm_b, Xg);
  // 2) frames -> token-major bf16
  tok_cvt_kernel<<<dim3(HW/64, C0/64, NB), 256, 0, stream>>>(Xg, X0);
  // 3) proj_in
  mfma_nt_kernel<1><<<dim3(C0PAD/128, NTOK/128), 256, 0, stream>>>(
      X0, Wpb, X1, C0, C0, 0, proj_in_b);
  // 4) expand, rows permuted frame->seq
  mfma_nt_kernel<2><<<dim3(CEXP/128, NTOK/128), 256, 0, stream>>>(
      X1, Web, U, CEXP, C0, 0, expand_b);
  // 5) chunked mamba
  for (int c = 0; c < NCHUNK; c++){
    const __hip_bfloat16* Uc = U + (size_t)c*TOK_PER*CEXP;
    mfma_nt_kernel<0><<<dim3(NPAD/128, TOK_PER/128), 256, 0, stream>>>(
        Uc, Wb, Z, D_IN_PROJ, CEXP, 0, nullptr);
    ssm_kernel<<<SEQ_PER, 512, 0, stream>>>(
        Z, conv_w, conv_b, dt_bias, A_log, Dvec, rms_w, Ycb);
    mfma_nt_kernel<3><<<dim3(CEXP/128, TOK_PER/128), 256, 0, stream>>>(
        Ycb, Wob, V, CEXP, D_INNER, c*TOK_PER, nullptr);
  }
  // 6) collapse (+bias)
  mfma_nt_kernel<1><<<dim3(C0PAD/128, NTOK/128), 256, 0, stream>>>(
      V, Wcb, C2, C0, CEXP, 0, collapse_b);
  // 7) proj_out (+bias)
  mfma_nt_kernel<1><<<dim3(C0PAD/128, NTOK/128), 256, 0, stream>>>(
      C2, Wqb, P, C0, C0, 0, proj_out_b);
  // 8) final residual transpose
  final_kernel<<<dim3(HW/64, C0/64, NB), 256, 0, stream>>>(P, x, gamma, out);
}